// Round 5
// baseline (154.823 us; speedup 1.0000x reference)
//
#include <hip/hip_runtime.h>
#include <stdint.h>

// Problem constants (B,C,D,H,W) = (2,1,128,256,256)
#define BB 2
#define DD 128
#define HH 256
#define WW 256
static constexpr int64_t N = (int64_t)BB * DD * HH * WW;   // 16,777,216
static constexpr int WPR    = WW / 64;                     // 4 words per row
static constexpr int NWORDS = BB * DD * HH * WPR;          // 262,144 words (2 MB)
static constexpr int RBLOCKS = 4096;                       // reduce grid (exact cover)

// ---------------------------------------------------------------------------
// K1: predicate + X-dilation (radius 3), bit-packed.
// One wave = 4 rows. Lane l: row-group l>>4, chunk c = l&15 -> 16 voxels
// (4 float4 loads, 64 B/thread). X-dilation via 48-bit window from lane+-1
// 16-bit chunks (7 shift-ORs). Pack 4 chunks -> uint64 in 2 shfl_xor steps.
// 4 cross-lane ops total per 64 B of input. No LDS.
// ---------------------------------------------------------------------------
__global__ __launch_bounds__(256) void mask_xdil(const float* __restrict__ tgt,
                                                 uint64_t* __restrict__ mask) {
    const int lane = threadIdx.x & 63;
    const int wave = threadIdx.x >> 6;
    const int rg   = lane >> 4;           // row within wave's group of 4
    const int c    = lane & 15;           // 16-voxel chunk within row
    const int row  = (blockIdx.x * 16) + wave * 4 + rg;   // 65,536 rows

    const float4* p = (const float4*)(tgt + (int64_t)row * WW + c * 16);
    float4 q0 = p[0], q1 = p[1], q2 = p[2], q3 = p[3];

    unsigned b = 0;
    b |= (q0.x > 0.0f && q0.x < 1.0f) ? 1u << 0  : 0u;
    b |= (q0.y > 0.0f && q0.y < 1.0f) ? 1u << 1  : 0u;
    b |= (q0.z > 0.0f && q0.z < 1.0f) ? 1u << 2  : 0u;
    b |= (q0.w > 0.0f && q0.w < 1.0f) ? 1u << 3  : 0u;
    b |= (q1.x > 0.0f && q1.x < 1.0f) ? 1u << 4  : 0u;
    b |= (q1.y > 0.0f && q1.y < 1.0f) ? 1u << 5  : 0u;
    b |= (q1.z > 0.0f && q1.z < 1.0f) ? 1u << 6  : 0u;
    b |= (q1.w > 0.0f && q1.w < 1.0f) ? 1u << 7  : 0u;
    b |= (q2.x > 0.0f && q2.x < 1.0f) ? 1u << 8  : 0u;
    b |= (q2.y > 0.0f && q2.y < 1.0f) ? 1u << 9  : 0u;
    b |= (q2.z > 0.0f && q2.z < 1.0f) ? 1u << 10 : 0u;
    b |= (q2.w > 0.0f && q2.w < 1.0f) ? 1u << 11 : 0u;
    b |= (q3.x > 0.0f && q3.x < 1.0f) ? 1u << 12 : 0u;
    b |= (q3.y > 0.0f && q3.y < 1.0f) ? 1u << 13 : 0u;
    b |= (q3.z > 0.0f && q3.z < 1.0f) ? 1u << 14 : 0u;
    b |= (q3.w > 0.0f && q3.w < 1.0f) ? 1u << 15 : 0u;

    unsigned L = (unsigned)__shfl_up((int)b, 1, 64);
    unsigned R = (unsigned)__shfl_down((int)b, 1, 64);
    if (c == 0)  L = 0;
    if (c == 15) R = 0;

    // window: bits 0..15 = left chunk, 16..31 = own, 32..47 = right.
    // voxel j (own) is window bit 16+j; dilated bit j = OR of bits 13+j..19+j.
    const uint64_t win = (uint64_t)L | ((uint64_t)b << 16) | ((uint64_t)R << 32);
    uint64_t v = 0;
    #pragma unroll
    for (int s = 0; s < 7; s++) v |= win >> (13 + s);
    unsigned dil = (unsigned)v & 0xFFFFu;

    // pack: chunks c..c+3 (c%4==0 lanes) -> one uint64, low chunk = low bits
    unsigned p1 = (unsigned)__shfl_xor((int)dil, 1, 64);
    unsigned x32 = (c & 1) ? (p1 | (dil << 16)) : (dil | (p1 << 16));
    unsigned p2 = (unsigned)__shfl_xor((int)x32, 2, 64);
    uint64_t x64 = (c & 2) ? ((uint64_t)p2 | ((uint64_t)x32 << 32))
                           : ((uint64_t)x32 | ((uint64_t)p2 << 32));

    if ((lane & 3) == 0)
        mask[(int64_t)row * WPR + (c >> 2)] = x64;
}

// ---------------------------------------------------------------------------
// K2: fused Y+Z dilation (radius 3 each) on the packed mask, LDS-tiled.
// ---------------------------------------------------------------------------
__global__ __launch_bounds__(256) void yz_dil(const uint64_t* __restrict__ in,
                                              uint64_t* __restrict__ out) {
    __shared__ uint64_t raw[22][23];   // +1 pad
    __shared__ uint64_t yd[22][17];    // +1 pad
    const int ty = threadIdx.x & 15;
    const int tz = threadIdx.x >> 4;
    const int y0 = blockIdx.x * 16;
    const int z0 = blockIdx.y * 16;
    const int b  = blockIdx.z >> 2;
    const int wx = blockIdx.z & 3;

    for (int idx = threadIdx.x; idx < 22 * 22; idx += 256) {
        const int zz = idx / 22, yy = idx % 22;
        const int gz = z0 - 3 + zz, gy = y0 - 3 + yy;
        uint64_t v = 0;
        if (gz >= 0 && gz < DD && gy >= 0 && gy < HH)
            v = in[(((int64_t)(b * DD + gz)) * HH + gy) * WPR + wx];
        raw[zz][yy] = v;
    }
    __syncthreads();

    for (int idx = threadIdx.x; idx < 22 * 16; idx += 256) {
        const int zz = idx >> 4, yy = idx & 15;
        uint64_t v = 0;
        #pragma unroll
        for (int d = 0; d < 7; d++) v |= raw[zz][yy + d];
        yd[zz][yy] = v;
    }
    __syncthreads();

    uint64_t v = 0;
    #pragma unroll
    for (int d = 0; d < 7; d++) v |= yd[tz + d][ty];
    out[(((int64_t)(b * DD + z0 + tz)) * HH + y0 + ty) * WPR + wx] = v;
}

// ---------------------------------------------------------------------------
// K3: weighted L1 partial reduction. Grid chosen so each thread does EXACTLY
// 4 float4-pairs (compile-time unrolled, 4 independent accumulators -> all
// loads issue up-front). One non-atomic double store per block.
// ---------------------------------------------------------------------------
__global__ __launch_bounds__(256) void reduce_loss(const float* __restrict__ inp,
                                                   const float* __restrict__ tgt,
                                                   const uint64_t* __restrict__ mask,
                                                   double* __restrict__ partials) {
    static constexpr int64_t STRIDE = (int64_t)RBLOCKS * 256;   // 1,048,576
    const int64_t i0 = (int64_t)blockIdx.x * 256 + threadIdx.x;

    float acc[4];
    #pragma unroll
    for (int u = 0; u < 4; u++) {
        const int64_t i = i0 + u * STRIDE;        // < N/4 = 4*STRIDE exactly
        float4 a = ((const float4*)inp)[i];
        float4 t = ((const float4*)tgt)[i];
        uint64_t w = mask[i >> 4];
        unsigned nib = (unsigned)(w >> ((i & 15) * 4)) & 0xFu;
        float s;
        s  = fabsf(t.x - a.x) * ((nib & 1u) ? 11.0f : 1.0f);
        s += fabsf(t.y - a.y) * ((nib & 2u) ? 11.0f : 1.0f);
        s += fabsf(t.z - a.z) * ((nib & 4u) ? 11.0f : 1.0f);
        s += fabsf(t.w - a.w) * ((nib & 8u) ? 11.0f : 1.0f);
        acc[u] = s;
    }
    float local = (acc[0] + acc[1]) + (acc[2] + acc[3]);

    #pragma unroll
    for (int off = 32; off > 0; off >>= 1)
        local += __shfl_down(local, off, 64);
    __shared__ float wsum[4];
    const int lane = threadIdx.x & 63;
    const int wv   = threadIdx.x >> 6;
    if (lane == 0) wsum[wv] = local;
    __syncthreads();
    if (threadIdx.x == 0)
        partials[blockIdx.x] = (double)(wsum[0] + wsum[1] + wsum[2] + wsum[3]);
}

// ---------------------------------------------------------------------------
// K4: sum 4096 double partials, divide by N.
// ---------------------------------------------------------------------------
__global__ __launch_bounds__(1024) void finalize(const double* __restrict__ partials,
                                                 float* __restrict__ out) {
    double local = 0.0;
    for (int i = threadIdx.x; i < RBLOCKS; i += 1024) local += partials[i];
    #pragma unroll
    for (int off = 32; off > 0; off >>= 1)
        local += __shfl_down(local, off, 64);
    __shared__ double ws[16];
    const int lane = threadIdx.x & 63;
    const int wv   = threadIdx.x >> 6;
    if (lane == 0) ws[wv] = local;
    __syncthreads();
    if (threadIdx.x == 0) {
        double s = 0.0;
        #pragma unroll
        for (int k = 0; k < 16; k++) s += ws[k];
        out[0] = (float)(s / (double)N);
    }
}

extern "C" void kernel_launch(void* const* d_in, const int* in_sizes, int n_in,
                              void* d_out, int out_size, void* d_ws, size_t ws_size,
                              hipStream_t stream) {
    const float* inp = (const float*)d_in[0];   // "input"
    const float* tgt = (const float*)d_in[1];   // "target"
    float* out = (float*)d_out;

    double*   partials = (double*)d_ws;                        // 32 KB (fully written)
    uint64_t* mask0 = (uint64_t*)((char*)d_ws + 64 * 1024);    // 2 MB
    uint64_t* mask1 = mask0 + NWORDS;                          // 2 MB

    mask_xdil<<<4096, 256, 0, stream>>>(tgt, mask0);           // 16 rows/block
    yz_dil<<<dim3(HH / 16, DD / 16, BB * WPR), 256, 0, stream>>>(mask0, mask1);
    reduce_loss<<<RBLOCKS, 256, 0, stream>>>(inp, tgt, mask1, partials);
    finalize<<<1, 1024, 0, stream>>>(partials, out);
}

// Round 6
// 151.465 us; speedup vs baseline: 1.0222x; 1.0222x over previous
//
#include <hip/hip_runtime.h>
#include <stdint.h>

// Problem constants (B,C,D,H,W) = (2,1,128,256,256)
#define BB 2
#define DD 128
#define HH 256
#define WW 256
static constexpr int64_t N = (int64_t)BB * DD * HH * WW;   // 16,777,216
static constexpr int WPR    = WW / 64;                     // 4 words per row
static constexpr int NWORDS = BB * DD * HH * WPR;          // 262,144 words (2 MB)
static constexpr int RBLOCKS = 4096;                       // reduce grid

// ---------------------------------------------------------------------------
// K1: predicate + X-dilation (radius 3), bit-packed via 4 ballots/row.
// One wave = one W-row. Lane l loads float4 l (1 KB/wave, coalesced).
// Ballot of component j is TRANSPOSED word W_j (bit l <-> voxel 4l+j).
// X-dilation on transposed words is wave-uniform SALU shift/OR. Lanes 0-3
// store the 4 words. Mask stays transposed until yz_dil fixes it up.
// ---------------------------------------------------------------------------
__global__ __launch_bounds__(256) void mask_xdil(const float* __restrict__ tgt,
                                                 uint64_t* __restrict__ mask) {
    const int wave = threadIdx.x >> 6;
    const int lane = threadIdx.x & 63;
    const int row  = blockIdx.x * 4 + wave;             // 65,536 rows

    float4 t = ((const float4*)(tgt + (int64_t)row * WW))[lane];

    const uint64_t W0 = __ballot(t.x > 0.0f && t.x < 1.0f);
    const uint64_t W1 = __ballot(t.y > 0.0f && t.y < 1.0f);
    const uint64_t W2 = __ballot(t.z > 0.0f && t.z < 1.0f);
    const uint64_t W3 = __ballot(t.w > 0.0f && t.w < 1.0f);

    const uint64_t U  = W0 | W1 | W2 | W3;
    const uint64_t D0 = U | ((W1 | W2 | W3) << 1);
    const uint64_t D1 = U | ((W2 | W3) << 1) | (W0 >> 1);
    const uint64_t D2 = U | (W3 << 1) | ((W0 | W1) >> 1);
    const uint64_t D3 = U | ((W0 | W1 | W2) >> 1);

    uint64_t d = D0;
    if (lane == 1) d = D1;
    if (lane == 2) d = D2;
    if (lane == 3) d = D3;
    if (lane < 4)
        mask[(int64_t)row * WPR + lane] = d;
}

__device__ __forceinline__ uint64_t spread4(uint64_t x) {   // bit i -> bit 4i
    x &= 0xFFFFull;
    x = (x | (x << 24)) & 0x000000FF000000FFull;
    x = (x | (x << 12)) & 0x000F000F000F000Full;
    x = (x | (x << 6))  & 0x0303030303030303ull;
    x = (x | (x << 3))  & 0x1111111111111111ull;
    return x;
}

// ---------------------------------------------------------------------------
// K2: fused Y+Z dilation (radius 3 each) on the transposed mask, LDS-tiled,
// all 4 words of each row per block; epilogue transposes bit order back to
// linear (4x spread4 per word) and stores 32 B/row contiguously.
// ---------------------------------------------------------------------------
__global__ __launch_bounds__(256) void yz_dil(const uint64_t* __restrict__ in,
                                              uint64_t* __restrict__ out) {
    __shared__ uint64_t raw[4][22][23];   // +1 pad
    __shared__ uint64_t yd[4][22][17];    // +1 pad
    const int ty = threadIdx.x & 15;
    const int tz = threadIdx.x >> 4;
    const int y0 = blockIdx.x * 16;
    const int z0 = blockIdx.y * 16;
    const int b  = blockIdx.z;

    for (int idx = threadIdx.x; idx < 22 * 22; idx += 256) {
        const int zz = idx / 22, yy = idx % 22;
        const int gz = z0 - 3 + zz, gy = y0 - 3 + yy;
        const bool ok = (gz >= 0 && gz < DD && gy >= 0 && gy < HH);
        const uint64_t* p = in + (((int64_t)(b * DD + gz)) * HH + gy) * WPR;
        #pragma unroll
        for (int j = 0; j < 4; j++)
            raw[j][zz][yy] = ok ? p[j] : 0ull;
    }
    __syncthreads();

    for (int idx = threadIdx.x; idx < 22 * 16; idx += 256) {
        const int zz = idx >> 4, yy = idx & 15;
        #pragma unroll
        for (int j = 0; j < 4; j++) {
            uint64_t v = 0;
            #pragma unroll
            for (int d = 0; d < 7; d++) v |= raw[j][zz][yy + d];
            yd[j][zz][yy] = v;
        }
    }
    __syncthreads();

    uint64_t D[4];
    #pragma unroll
    for (int j = 0; j < 4; j++) {
        uint64_t v = 0;
        #pragma unroll
        for (int d = 0; d < 7; d++) v |= yd[j][tz + d][ty];
        D[j] = v;
    }

    // transposed -> linear: linear word wx bit m = bit(16wx + m>>2) of D[m&3]
    uint64_t* o = out + (((int64_t)(b * DD + z0 + tz)) * HH + y0 + ty) * WPR;
    #pragma unroll
    for (int wx = 0; wx < 4; wx++) {
        uint64_t r = 0;
        #pragma unroll
        for (int j = 0; j < 4; j++)
            r |= spread4(D[j] >> (16 * wx)) << j;
        o[wx] = r;
    }
}

// ---------------------------------------------------------------------------
// K3: weighted L1 partial reduction (R4-proven form). float4 loads, mask
// nibble per float4, wave shuffle -> LDS -> one non-atomic double store.
// ---------------------------------------------------------------------------
__global__ __launch_bounds__(256) void reduce_loss(const float* __restrict__ inp,
                                                   const float* __restrict__ tgt,
                                                   const uint64_t* __restrict__ mask,
                                                   double* __restrict__ partials) {
    const int64_t nvec = N / 4;
    const int64_t stride = (int64_t)RBLOCKS * 256;
    float local = 0.0f;
    for (int64_t i = (int64_t)blockIdx.x * 256 + threadIdx.x; i < nvec; i += stride) {
        float4 a = ((const float4*)inp)[i];
        float4 t = ((const float4*)tgt)[i];
        uint64_t w = mask[i >> 4];
        unsigned nib = (unsigned)(w >> ((i & 15) * 4)) & 0xFu;
        float s;
        s  = fabsf(t.x - a.x) * ((nib & 1u) ? 11.0f : 1.0f);
        s += fabsf(t.y - a.y) * ((nib & 2u) ? 11.0f : 1.0f);
        s += fabsf(t.z - a.z) * ((nib & 4u) ? 11.0f : 1.0f);
        s += fabsf(t.w - a.w) * ((nib & 8u) ? 11.0f : 1.0f);
        local += s;
    }
    #pragma unroll
    for (int off = 32; off > 0; off >>= 1)
        local += __shfl_down(local, off, 64);
    __shared__ float wsum[4];
    const int lane = threadIdx.x & 63;
    const int wv   = threadIdx.x >> 6;
    if (lane == 0) wsum[wv] = local;
    __syncthreads();
    if (threadIdx.x == 0)
        partials[blockIdx.x] = (double)(wsum[0] + wsum[1] + wsum[2] + wsum[3]);
}

// ---------------------------------------------------------------------------
// K4: sum 4096 double partials, divide by N.
// ---------------------------------------------------------------------------
__global__ __launch_bounds__(1024) void finalize(const double* __restrict__ partials,
                                                 float* __restrict__ out) {
    double local = 0.0;
    for (int i = threadIdx.x; i < RBLOCKS; i += 1024) local += partials[i];
    #pragma unroll
    for (int off = 32; off > 0; off >>= 1)
        local += __shfl_down(local, off, 64);
    __shared__ double ws[16];
    const int lane = threadIdx.x & 63;
    const int wv   = threadIdx.x >> 6;
    if (lane == 0) ws[wv] = local;
    __syncthreads();
    if (threadIdx.x == 0) {
        double s = 0.0;
        #pragma unroll
        for (int k = 0; k < 16; k++) s += ws[k];
        out[0] = (float)(s / (double)N);
    }
}

extern "C" void kernel_launch(void* const* d_in, const int* in_sizes, int n_in,
                              void* d_out, int out_size, void* d_ws, size_t ws_size,
                              hipStream_t stream) {
    const float* inp = (const float*)d_in[0];   // "input"
    const float* tgt = (const float*)d_in[1];   // "target"
    float* out = (float*)d_out;

    double*   partials = (double*)d_ws;                        // 32 KB (fully written)
    uint64_t* mask0 = (uint64_t*)((char*)d_ws + 64 * 1024);    // 2 MB (transposed)
    uint64_t* mask1 = mask0 + NWORDS;                          // 2 MB (linear)

    mask_xdil<<<16384, 256, 0, stream>>>(tgt, mask0);          // 4 rows/block
    yz_dil<<<dim3(HH / 16, DD / 16, BB), 256, 0, stream>>>(mask0, mask1);
    reduce_loss<<<RBLOCKS, 256, 0, stream>>>(inp, tgt, mask1, partials);
    finalize<<<1, 1024, 0, stream>>>(partials, out);
}